// Round 5
// baseline (628.137 us; speedup 1.0000x reference)
//
#include <hip/hip_runtime.h>

#define B_  16
#define S_  256
#define G_  2048
#define D_  512
#define H_  8
#define DK_ 64
#define E_  8

typedef _Float16 half8  __attribute__((ext_vector_type(8)));
typedef _Float16 half4v __attribute__((ext_vector_type(4)));
typedef float    floatx4 __attribute__((ext_vector_type(4)));
typedef float    floatx16 __attribute__((ext_vector_type(16)));

// async global->LDS, 16B per lane; LDS dest = wave-uniform base + lane*16
#define GLDS(g, l) __builtin_amdgcn_global_load_lds( \
    (const __attribute__((address_space(1))) void*)(g), \
    (__attribute__((address_space(3))) void*)(l), 16, 0, 0)

// ---------------------------------------------------------------------------
// split fp32 -> hi/lo f16 (x = hi + lo, residual ~2^-22 rel)
// ---------------------------------------------------------------------------
__global__ void __launch_bounds__(256) split_f16(
    const float* __restrict__ src, _Float16* __restrict__ hi,
    _Float16* __restrict__ lo, int n4)
{
    int i = blockIdx.x * 256 + threadIdx.x;
    if (i >= n4) return;
    float4 v = ((const float4*)src)[i];
    half4v h, l;
    h[0] = (_Float16)v.x; h[1] = (_Float16)v.y;
    h[2] = (_Float16)v.z; h[3] = (_Float16)v.w;
    l[0] = (_Float16)(v.x - (float)h[0]); l[1] = (_Float16)(v.y - (float)h[1]);
    l[2] = (_Float16)(v.z - (float)h[2]); l[3] = (_Float16)(v.w - (float)h[3]);
    ((half4v*)hi)[i] = h;
    ((half4v*)lo)[i] = l;
}

// ---------------------------------------------------------------------------
// transpose + split: dst[c][r] = src[z][r][c], dst ld = R. (weights pack)
// grid: (C/32, R/32, Z)
// ---------------------------------------------------------------------------
__global__ void __launch_bounds__(256) transpose_split(
    const float* __restrict__ src, _Float16* __restrict__ hi,
    _Float16* __restrict__ lo, int R, int C)
{
    __shared__ float T[32][33];
    const int tid = threadIdx.x;
    const long zo = (long)blockIdx.z * R * C;
    const int r0 = blockIdx.y * 32, c0 = blockIdx.x * 32;
#pragma unroll
    for (int p = 0; p < 4; ++p) {
        int i = tid + p * 256;
        int lr = i >> 5, lc = i & 31;
        T[lr][lc] = src[zo + (long)(r0 + lr) * C + (c0 + lc)];
    }
    __syncthreads();
#pragma unroll
    for (int p = 0; p < 4; ++p) {
        int i = tid + p * 256;
        int orr = i >> 5, oc = i & 31;
        float v = T[oc][orr];
        _Float16 h = (_Float16)v;
        long o = zo + (long)(c0 + orr) * R + (r0 + oc);
        hi[o] = h;
        lo[o] = (_Float16)(v - (float)h);
    }
}

// ---------------------------------------------------------------------------
// mask -> per-64g-tile 64-bit bitmap (bit g set iff mask byte nonzero)
// grid 2 x 256: thread t handles (b = t>>5, tile = t&31); ulong-vector loads
// ---------------------------------------------------------------------------
__global__ void __launch_bounds__(256) mask_bitmap(
    const unsigned char* __restrict__ mask, unsigned long long* __restrict__ bmp)
{
    const int t = blockIdx.x * 256 + threadIdx.x;
    const int b = t >> 5, tile = t & 31;
    const unsigned long long* m8 =
        (const unsigned long long*)(mask + (long)b * G_ + tile * 64);
    unsigned long long v = 0ULL;
#pragma unroll
    for (int i = 0; i < 8; ++i) {
        const unsigned long long w = m8[i];
#pragma unroll
        for (int j = 0; j < 8; ++j)
            v |= (((w >> (8 * j)) & 0xFFULL) ? 1ULL : 0ULL) << (8 * i + j);
    }
    bmp[t] = v;
}

// ---------------------------------------------------------------------------
// f16x3 MFMA GEMM (NT): C = alpha * (Ah+Al)(M x 512) @ (Bh+Bl)(N x 512)^T
// 128x128 tile, 4 waves (64x64 each, 2x2 of 32x32x16 MFMA), BK=32.
// LDS rows are 64B (4 granules of 16B); granule slot s holds data granule
// s ^ ((row>>1)&3)  (applied on GLOBAL source + on fragment read) so the
// 32-lane b128 fragment reads are bank-conflict-free (bank-quad
// 4*(row&1)+slot is a permutation of 0..7 per 8-lane group).
// A,B k-major ld=512. C (fp32) nullable; split output (Chi/Clo) nullable.
// z: A rows += z*sAz, B rows += z*sBz, C += z*sCz.
// ---------------------------------------------------------------------------
__global__ void __launch_bounds__(256) gemm_f16x3(
    const _Float16* __restrict__ Ah, const _Float16* __restrict__ Al,
    const _Float16* __restrict__ Bh, const _Float16* __restrict__ Bl,
    float* __restrict__ C, _Float16* __restrict__ Chi, _Float16* __restrict__ Clo,
    long ldc, long sAz, long sBz, long sCz, float alpha)
{
    __shared__ _Float16 Ash[128 * 32], Asl[128 * 32];
    __shared__ _Float16 Bsh[128 * 32], Bsl[128 * 32];
    const int tid = threadIdx.x;
    const int w = tid >> 6, lane = tid & 63;
    const int lh = lane >> 5, ln = lane & 31;
    const int wm = (w >> 1) * 64, wn = (w & 1) * 64;
    const int z = blockIdx.z;
    const long m0 = (long)blockIdx.y * 128;
    const long n0 = (long)blockIdx.x * 128;
    const _Float16* Agh = Ah + (z * sAz + m0) * 512;
    const _Float16* Agl = Al + (z * sAz + m0) * 512;
    const _Float16* Bgh = Bh + (z * sBz + n0) * 512;
    const _Float16* Bgl = Bl + (z * sBz + n0) * 512;

    // staging role: lane covers (row-in-chunk = lane>>2, slot = lane&3)
    const int rowc = lane >> 2, slot = lane & 3;

    floatx16 acc[2][2] = {};

    for (int k0 = 0; k0 < 512; k0 += 32) {
#pragma unroll
        for (int cc = 0; cc < 2; ++cc) {           // each wave stages 2 of 8 chunks
            const int c = 2 * w + cc;
            const int trow = c * 16 + rowc;
            const int g = slot ^ ((trow >> 1) & 3);     // inverse swizzle on source
            const long go = (long)trow * 512 + k0 + g * 8;
            GLDS(Agh + go, Ash + c * 512);
            GLDS(Agl + go, Asl + c * 512);
            GLDS(Bgh + go, Bsh + c * 512);
            GLDS(Bgl + go, Bsl + c * 512);
        }
        asm volatile("s_waitcnt vmcnt(0)" ::: "memory");
        __syncthreads();

        half8 a_h[2][2], a_l[2][2], b_h[2][2], b_l[2][2];
#pragma unroll
        for (int i = 0; i < 2; ++i)
#pragma unroll
            for (int kk = 0; kk < 2; ++kk) {
                const int ra = wm + i * 32 + ln;
                const int sa = (kk * 2 + lh) ^ ((ra >> 1) & 3);
                a_h[i][kk] = *(const half8*)&Ash[ra * 32 + sa * 8];
                a_l[i][kk] = *(const half8*)&Asl[ra * 32 + sa * 8];
                const int rb = wn + i * 32 + ln;
                const int sb = (kk * 2 + lh) ^ ((rb >> 1) & 3);
                b_h[i][kk] = *(const half8*)&Bsh[rb * 32 + sb * 8];
                b_l[i][kk] = *(const half8*)&Bsl[rb * 32 + sb * 8];
            }
#pragma unroll
        for (int i = 0; i < 2; ++i)
#pragma unroll
            for (int j = 0; j < 2; ++j)
#pragma unroll
                for (int kk = 0; kk < 2; ++kk) {
                    acc[i][j] = __builtin_amdgcn_mfma_f32_32x32x16_f16(a_h[i][kk], b_h[j][kk], acc[i][j], 0, 0, 0);
                    acc[i][j] = __builtin_amdgcn_mfma_f32_32x32x16_f16(a_h[i][kk], b_l[j][kk], acc[i][j], 0, 0, 0);
                    acc[i][j] = __builtin_amdgcn_mfma_f32_32x32x16_f16(a_l[i][kk], b_h[j][kk], acc[i][j], 0, 0, 0);
                }
        __syncthreads();
    }

    // C/D layout (32x32): col = ln, row = (r&3) + 8*(r>>2) + 4*lh
#pragma unroll
    for (int i = 0; i < 2; ++i)
#pragma unroll
        for (int r = 0; r < 16; ++r) {
            const long row = m0 + wm + i * 32 + (r & 3) + 8 * (r >> 2) + 4 * lh;
#pragma unroll
            for (int j = 0; j < 2; ++j) {
                float v = acc[i][j][r] * alpha;
                const long o = (long)z * sCz + row * ldc + n0 + wn + j * 32 + ln;
                if (C) C[o] = v;
                if (Chi) {
                    _Float16 hh = (_Float16)v;
                    Chi[o] = hh;
                    Clo[o] = (_Float16)(v - (float)hh);
                }
            }
        }
}

// ---------------------------------------------------------------------------
// MFMA flash attention, f16x3, 32x32x16 MFMA, swapped-operand QK^T so P is
// lane-local (no P LDS round-trip). 256 thr = 4 waves; wave owns 32 s-rows;
// block = 128 s x 512 g (G split in 4 quarters). Unnormalized partial O +
// row-sums out (no-max softmax => partials add); combine_flash normalizes.
// ---------------------------------------------------------------------------
__global__ void __launch_bounds__(256) flash_mfma(
    const _Float16* __restrict__ qh, const _Float16* __restrict__ qlo,
    const _Float16* __restrict__ kh, const _Float16* __restrict__ kl,
    const _Float16* __restrict__ vh, const _Float16* __restrict__ vl,
    const unsigned long long* __restrict__ bmp,
    float* __restrict__ Opart, float* __restrict__ Lpart)
{
    __shared__ half8 KH[512], KL[512], VH[512], VL[512];   // 64 rows x 8 gran, 32KB
    const int tid = threadIdx.x;
    const int wid = tid >> 6, lane = tid & 63;
    const int lh = lane >> 5, ln = lane & 31;
    const int head = blockIdx.y, b = blockIdx.z;
    const int sblk = blockIdx.x & 1, gq = blockIdx.x >> 1;   // 2 s-halves x 4 g-quarters
    const long tok0 = (long)b * S_ + sblk * 128 + wid * 32;

    // Q fragments (B-operand: col = ln = s, k = ks*16 + lh*8 + e), loaded once
    const long qoff = (tok0 + ln) * 512 + head * 64 + lh * 8;
    half8 qfh[4], qfl[4];
#pragma unroll
    for (int ks = 0; ks < 4; ++ks) {
        qfh[ks] = *(const half8*)(qh + qoff + ks * 16);
        qfl[ks] = *(const half8*)(qlo + qoff + ks * 16);
    }

    // staging roles: wave wid stages row-chunks c = 2*wid, 2*wid+1 (8 rows x 8 gran)
    const int srow_lo = lane >> 3;          // row within chunk
    const int sgs = lane & 7;               // dest granule slot (linear in lane)
    const long kgK = (long)b * G_ * 512 + head * 64;
    const long kgV = (long)head * 64 * (B_ * G_) + (long)b * G_;

    floatx16 accO[2] = {};
    float lsum = 0.f;

    for (int t = 0; t < 8; ++t) {
        const int g0 = gq * 512 + t * 64;
        // ---- stage K/V tile: linear LDS dest, inverse-swizzled global source
#pragma unroll
        for (int cc = 0; cc < 2; ++cc) {
            const int c = 2 * wid + cc;
            const int r = c * 8 + srow_lo;
            const int gs = sgs ^ (r & 7);
            const long ko = kgK + (long)(g0 + r) * 512 + gs * 8;
            const long vo = kgV + (long)r * (B_ * G_) + g0 + gs * 8;
            GLDS(kh + ko, KH + c * 64);
            GLDS(kl + ko, KL + c * 64);
            GLDS(vh + vo, VH + c * 64);
            GLDS(vl + vo, VL + c * 64);
        }
        asm volatile("s_waitcnt vmcnt(0)" ::: "memory");
        __syncthreads();

        // ---- scores^T = K Q^T (A=K, B=Q): lane holds col s=ln, rows=g spread
        floatx16 accS[2] = {};
#pragma unroll
        for (int gt = 0; gt < 2; ++gt) {
            const int grow = gt * 32 + ln;
            const int gbase = grow * 8, gswz = grow & 7;
#pragma unroll
            for (int ks = 0; ks < 4; ++ks) {
                const int gi = gbase + ((ks * 2 + lh) ^ gswz);
                half8 kbh = KH[gi], kbl = KL[gi];
                accS[gt] = __builtin_amdgcn_mfma_f32_32x32x16_f16(kbh, qfh[ks], accS[gt], 0, 0, 0);
                accS[gt] = __builtin_amdgcn_mfma_f32_32x32x16_f16(kbh, qfl[ks], accS[gt], 0, 0, 0);
                accS[gt] = __builtin_amdgcn_mfma_f32_32x32x16_f16(kbl, qfh[ks], accS[gt], 0, 0, 0);
            }
        }

        // ---- mask via uniform bitmap (skipped entirely when no bits set) ----
        const unsigned long long bm = bmp[(b << 5) + (g0 >> 6)];
        if (bm != 0ULL) {
            const unsigned w0 = lh ? ((unsigned)bm >> 4) : (unsigned)bm;
            const unsigned w1 = lh ? ((unsigned)(bm >> 32) >> 4) : (unsigned)(bm >> 32);
#pragma unroll
            for (int gt = 0; gt < 2; ++gt) {
                const unsigned wsel = gt ? w1 : w0;
#pragma unroll
                for (int r = 0; r < 16; ++r) {
                    const int sh = (r & 3) + 8 * (r >> 2);
                    if ((wsel >> sh) & 1u) accS[gt][r] = -1.0e9f;
                }
            }
        }

        // ---- p = exp2(s); row-sum = in-lane add + one cross-half exchange ----
        float rs = 0.f;
#pragma unroll
        for (int gt = 0; gt < 2; ++gt)
#pragma unroll
            for (int r = 0; r < 16; ++r) {
                const float pv = __builtin_exp2f(accS[gt][r]);
                accS[gt][r] = pv;
                rs += pv;
            }
        rs += __shfl_xor(rs, 32);
        lsum += rs;

        // ---- O += P V : assemble A-frag of P in registers (shfl across halves)
#pragma unroll
        for (int gt = 0; gt < 2; ++gt)
#pragma unroll
            for (int w = 0; w < 2; ++w) {
                half8 ph, pl;
#pragma unroll
                for (int j = 0; j < 4; ++j) {
                    const float pA = accS[gt][8 * w + j];
                    const float pB = accS[gt][8 * w + 4 + j];
                    const float snd = lh ? pA : pB;
                    const float rcv = __shfl_xor(snd, 32);
                    const float e03 = lh ? rcv : pA;
                    const float e47 = lh ? pB : rcv;
                    float hi = __uint_as_float(__float_as_uint(e03) & 0xFFFFE000u);
                    ph[j] = (_Float16)hi;
                    pl[j] = (_Float16)(e03 - hi);
                    hi = __uint_as_float(__float_as_uint(e47) & 0xFFFFE000u);
                    ph[4 + j] = (_Float16)hi;
                    pl[4 + j] = (_Float16)(e47 - hi);
                }
                const int gvb = gt * 4 + w * 2 + lh;
#pragma unroll
                for (int nt = 0; nt < 2; ++nt) {
                    const int vrow = nt * 32 + ln;
                    const int gi = vrow * 8 + (gvb ^ (vrow & 7));
                    half8 vbh = VH[gi], vbl = VL[gi];
                    accO[nt] = __builtin_amdgcn_mfma_f32_32x32x16_f16(ph, vbh, accO[nt], 0, 0, 0);
                    accO[nt] = __builtin_amdgcn_mfma_f32_32x32x16_f16(ph, vbl, accO[nt], 0, 0, 0);
                    accO[nt] = __builtin_amdgcn_mfma_f32_32x32x16_f16(pl, vbh, accO[nt], 0, 0, 0);
                }
            }
        __syncthreads();
    }

    // ---- epilogue: unnormalized partial O + row-sums for this G-quarter ----
    float* Op = Opart + (long)gq * (4096L * 512);
#pragma unroll
    for (int nt = 0; nt < 2; ++nt)
#pragma unroll
        for (int r = 0; r < 16; ++r) {
            const int s = (r & 3) + 8 * (r >> 2) + 4 * lh;
            Op[(tok0 + s) * 512 + head * 64 + nt * 32 + ln] = accO[nt][r];
        }
    if (lane < 32)
        Lpart[(long)gq * 32768 + (tok0 + lane) * 8 + head] = lsum;
}

// ---------------------------------------------------------------------------
// combine the four G-quarter partials: heads = sum(O)/sum(l), split hi/lo f16
// ---------------------------------------------------------------------------
__global__ void __launch_bounds__(256) combine_flash(
    const float* __restrict__ Op, const float* __restrict__ Lp,
    _Float16* __restrict__ hd_hi, _Float16* __restrict__ hd_lo)
{
    const int idx = blockIdx.x * 256 + threadIdx.x;
    const int n = idx >> 7;
    const int c = (idx & 127) * 4;
    const int h = c >> 6;
    float l = 0.f;
#pragma unroll
    for (int q = 0; q < 4; ++q) l += Lp[q * 32768 + (long)n * 8 + h];
    const float inv = 1.0f / l;
    float4 a = *(const float4*)(Op + (long)n * 512 + c);
#pragma unroll
    for (int q = 1; q < 4; ++q) {
        float4 d = *(const float4*)(Op + (long)q * 2097152 + (long)n * 512 + c);
        a.x += d.x; a.y += d.y; a.z += d.z; a.w += d.w;
    }
    const float ox = a.x * inv, oy = a.y * inv, oz = a.z * inv, ow = a.w * inv;
    half4v hh, ll;
    hh[0] = (_Float16)ox; hh[1] = (_Float16)oy;
    hh[2] = (_Float16)oz; hh[3] = (_Float16)ow;
    ll[0] = (_Float16)(ox - (float)hh[0]); ll[1] = (_Float16)(oy - (float)hh[1]);
    ll[2] = (_Float16)(oz - (float)hh[2]); ll[3] = (_Float16)(ow - (float)hh[3]);
    *(half4v*)(hd_hi + (long)n * 512 + c) = hh;
    *(half4v*)(hd_lo + (long)n * 512 + c) = ll;
}

// ---------------------------------------------------------------------------
// Gate: logits = glimpse @ w_gate (glimpse as hi/lo f16), top-2, softmax
// 64 blocks x 64 tokens (256 thr: all stage, wave 0 computes) -> gates[n][8]
// ---------------------------------------------------------------------------
__global__ void __launch_bounds__(256) gate_topk(
    const _Float16* __restrict__ Xh, const _Float16* __restrict__ Xl,
    const float* __restrict__ wg, float* __restrict__ gates)
{
    __shared__ float W[512][8];
    __shared__ float Xs[64][37];
    const int tid = threadIdx.x;
    const int n0 = blockIdx.x * 64;
#pragma unroll
    for (int p = 0; p < 16; ++p) ((float*)W)[tid + p * 256] = wg[tid + p * 256];

    float acc[8] = {};
    for (int dc = 0; dc < 512; dc += 32) {
        __syncthreads();
#pragma unroll
        for (int p = 0; p < 2; ++p) {
            int f = tid + p * 256;
            int row = f >> 3, c4 = f & 7;
            long o = (long)(n0 + row) * 512 + dc + 4 * c4;
            half4v hv = *(const half4v*)(Xh + o);
            half4v lv = *(const half4v*)(Xl + o);
#pragma unroll
            for (int i = 0; i < 4; ++i) Xs[row][4 * c4 + i] = (float)hv[i] + (float)lv[i];
        }
        __syncthreads();
        if (tid < 64) {
            for (int d2 = 0; d2 < 32; ++d2) {
                float xv = Xs[tid][d2];
#pragma unroll
                for (int e = 0; e < 8; ++e) acc[e] += xv * W[dc + d2][e];
            }
        }
    }
    if (tid < 64) {
        float v1 = -3.0e38f; int i1 = 0;
#pragma unroll
        for (int e = 0; e < 8; ++e) if (acc[e] > v1) { v1 = acc[e]; i1 = e; }
        float v2 = -3.0e38f; int i2 = -1;
#pragma unroll
        for (int e = 0; e < 8; ++e) if (e != i1 && acc[e] > v2) { v2 = acc[e]; i2 = e; }
        float t = __expf(v2 - v1);
        float g1 = 1.0f / (1.0f + t);
        float g2 = t / (1.0f + t);
#pragma unroll
        for (int e = 0; e < 8; ++e)
            gates[(long)(n0 + tid) * 8 + e] = (e == i1) ? g1 : ((e == i2) ? g2 : 0.0f);
    }
}

// ---------------------------------------------------------------------------
// combine: gm = sum_e gates[n][e] * eo[e][n][:]  -> split hi/lo f16
// ---------------------------------------------------------------------------
__global__ void __launch_bounds__(256) combine_moe(
    const float* __restrict__ eo, const float* __restrict__ gates,
    _Float16* __restrict__ gh, _Float16* __restrict__ gl)
{
    const int idx = blockIdx.x * 256 + threadIdx.x;
    const int n = idx >> 7;
    const int c = (idx & 127) * 4;
    float g[8];
#pragma unroll
    for (int e = 0; e < 8; ++e) g[e] = gates[(long)n * 8 + e];
    float ax = 0.f, ay = 0.f, az = 0.f, aw = 0.f;
#pragma unroll
    for (int e = 0; e < 8; ++e) {
        if (g[e] != 0.0f) {
            float4 v = *(const float4*)(eo + (long)e * 2097152 + (long)n * 512 + c);
            ax += g[e] * v.x; ay += g[e] * v.y; az += g[e] * v.z; aw += g[e] * v.w;
        }
    }
    half4v h, l;
    h[0] = (_Float16)ax; h[1] = (_Float16)ay; h[2] = (_Float16)az; h[3] = (_Float16)aw;
    l[0] = (_Float16)(ax - (float)h[0]); l[1] = (_Float16)(ay - (float)h[1]);
    l[2] = (_Float16)(az - (float)h[2]); l[3] = (_Float16)(aw - (float)h[3]);
    *(half4v*)(gh + (long)n * 512 + c) = h;
    *(half4v*)(gl + (long)n * 512 + c) = l;
}

// ---------------------------------------------------------------------------
extern "C" void kernel_launch(void* const* d_in, const int* in_sizes, int n_in,
                              void* d_out, int out_size, void* d_ws, size_t ws_size,
                              hipStream_t stream) {
    const float* query     = (const float*)d_in[0];
    const float* key       = (const float*)d_in[1];
    // d_in[2] = value: UNUSED by the reference (V is projected from `key`)
    const float* logit_key = (const float*)d_in[3];
    const unsigned char* mask = (const unsigned char*)d_in[4];
    const float* Wq = (const float*)d_in[5];
    const float* Wk = (const float*)d_in[6];
    const float* Wv = (const float*)d_in[7];
    const float* Wo = (const float*)d_in[8];
    const float* wg = (const float*)d_in[9];
    const float* Ew = (const float*)d_in[10];
    float* out = (float*)d_out;

    // ---- workspace map (1 MB = 1048576 B); aliases annotated ----
    const size_t MBy = 1048576;
    char* W = (char*)d_ws;
    _Float16* q_hi  = (_Float16*)(W + 0 * MBy);    // projected Q (scaled), 4 MB each
    _Float16* q_lo  = (_Float16*)(W + 4 * MBy);
    _Float16* kp_hi = (_Float16*)(W + 8 * MBy);    // projected K, 32 MB each
    _Float16* kp_lo = (_Float16*)(W + 40 * MBy);
    _Float16* vt_hi = (_Float16*)(W + 72 * MBy);   // projected V^T [512][32768]
    _Float16* vt_lo = (_Float16*)(W + 104 * MBy);
    _Float16* kin_hi = (_Float16*)(W + 136 * MBy); // key split (dead after VT-proj)
    _Float16* kin_lo = (_Float16*)(W + 168 * MBy);
    float*    Opart = (float*)(W + 136 * MBy);     // flash partial O, 4x8MB (alias kin)
    float*    Lpart = (float*)(W + 168 * MBy);     // flash partial row-sums, 4x128KB
    float*    eo    = (float*)(W + 136 * MBy);     // expert_out 64MB (alias, after)
    _Float16* lk_hi = (_Float16*)(W + 136 * MBy);  // logit_key split (after combine)
    _Float16* lk_lo = (_Float16*)(W + 168 * MBy);
    _Float16* wq_hi = (_Float16*)(W + 204 * MBy);
    _Float16* wq_lo = (_Float16*)(W + 204 * MBy + 524288);
    _Float16* wk_hi = (_Float16*)(W + 205 * MBy);
    _Float16* wk_lo = (_Float16*)(W + 205 * MBy + 524288);
    _Float16* wv_hi = (_Float16*)(W + 206 * MBy);
    _Float16* wv_lo = (_Float16*)(W + 206 * MBy + 524288);
    _Float16* wo_hi = (_Float16*)(W + 207 * MBy);
    _Float16* wo_lo = (_Float16*)(W + 207 * MBy + 524288);
    _Float16* ew_hi = (_Float16*)(W + 208 * MBy);
    _Float16* ew_lo = (_Float16*)(W + 212 * MBy);
    _Float16* qi_hi = (_Float16*)(W + 216 * MBy);  // query split (dead after Q-proj)
    _Float16* qi_lo = (_Float16*)(W + 220 * MBy);
    _Float16* hd_hi = (_Float16*)(W + 216 * MBy);  // heads (alias qi, after)
    _Float16* hd_lo = (_Float16*)(W + 220 * MBy);
    _Float16* gl_hi = (_Float16*)(W + 224 * MBy);  // glimpse
    _Float16* gl_lo = (_Float16*)(W + 228 * MBy);
    _Float16* gm_hi = (_Float16*)(W + 232 * MBy);  // moe output
    _Float16* gm_lo = (_Float16*)(W + 236 * MBy);
    float*    gates = (float*)(W + 240 * MBy);     // 128 KB
    unsigned long long* bmp = (unsigned long long*)(W + 240 * MBy + 131072); // 4 KB

    dim3 blk(256);

    // ---- input splits / weight packs / mask bitmap ----
    split_f16<<<dim3(16384), blk, 0, stream>>>(key, kin_hi, kin_lo, 4194304);
    split_f16<<<dim3(2048), blk, 0, stream>>>(query, qi_hi, qi_lo, 524288);
    mask_bitmap<<<dim3(2), blk, 0, stream>>>(mask, bmp);
    transpose_split<<<dim3(2, 16, 8), blk, 0, stream>>>(Wq, wq_hi, wq_lo, 512, 64);
    transpose_split<<<dim3(2, 16, 8), blk, 0, stream>>>(Wk, wk_hi, wk_lo, 512, 64);
    transpose_split<<<dim3(2, 16, 8), blk, 0, stream>>>(Wv, wv_hi, wv_lo, 512, 64);
    transpose_split<<<dim3(16, 16, 1), blk, 0, stream>>>(Wo, wo_hi, wo_lo, 512, 512);
    transpose_split<<<dim3(16, 16, 8), blk, 0, stream>>>(Ew, ew_hi, ew_lo, 512, 512);

    // ---- projections (f16x3 MFMA, f16 hi/lo outputs only) ----
    // Q scaled by log2e/sqrt(DK) so flash uses exp2 with no per-score multiply
    gemm_f16x3<<<dim3(4, 32, 1), blk, 0, stream>>>(
        qi_hi, qi_lo, wq_hi, wq_lo, nullptr, q_hi, q_lo, 512, 0, 0, 0,
        0.1803368801111204f);
    gemm_f16x3<<<dim3(4, 256, 1), blk, 0, stream>>>(
        kin_hi, kin_lo, wk_hi, wk_lo, nullptr, kp_hi, kp_lo, 512, 0, 0, 0, 1.0f);
    // V^T = Wv^T @ key^T : A = wv pack (512x512 k-major), B = key split
    gemm_f16x3<<<dim3(256, 4, 1), blk, 0, stream>>>(
        wv_hi, wv_lo, kin_hi, kin_lo, nullptr, vt_hi, vt_lo, (long)B_ * G_,
        0, 0, 0, 1.0f);

    // ---- attention (32x32 MFMA f16x3, lane-local P, G split in 4) ----
    flash_mfma<<<dim3(8, H_, B_), blk, 0, stream>>>(
        q_hi, q_lo, kp_hi, kp_lo, vt_hi, vt_lo, bmp, Opart, Lpart);
    combine_flash<<<dim3(2048), blk, 0, stream>>>(Opart, Lpart, hd_hi, hd_lo);

    // ---- Wo merge -> glimpse (hi/lo) ----
    gemm_f16x3<<<dim3(4, 32, 1), blk, 0, stream>>>(
        hd_hi, hd_lo, wo_hi, wo_lo, nullptr, gl_hi, gl_lo, 512, 0, 0, 0, 1.0f);

    // ---- gating ----
    gate_topk<<<dim3(64), blk, 0, stream>>>(gl_hi, gl_lo, wg, gates);

    // ---- MoE experts (dense over e; gates re-zero non-top2) ----
    gemm_f16x3<<<dim3(4, 32, 8), blk, 0, stream>>>(
        gl_hi, gl_lo, ew_hi, ew_lo, eo, nullptr, nullptr, 512, 0, 512, 2097152, 1.0f);

    // ---- gate-weighted combine -> gm (hi/lo) ----
    combine_moe<<<dim3(2048), blk, 0, stream>>>(eo, gates, gm_hi, gm_lo);

    // ---- logit_key split (after eo consumed; aliases its region) ----
    split_f16<<<dim3(16384), blk, 0, stream>>>(logit_key, lk_hi, lk_lo, 4194304);

    // ---- final logits: out[b] = gm[b] @ lk[b]^T / sqrt(512) ----
    gemm_f16x3<<<dim3(16, 2, 16), blk, 0, stream>>>(
        gm_hi, gm_lo, lk_hi, lk_lo, out, nullptr, nullptr, 2048,
        256, 2048, 524288, 0.04419417382415922f);
}

// Round 6
// 595.849 us; speedup vs baseline: 1.0542x; 1.0542x over previous
//
#include <hip/hip_runtime.h>

#define B_  16
#define S_  256
#define G_  2048
#define D_  512
#define H_  8
#define DK_ 64
#define E_  8

typedef _Float16 half8  __attribute__((ext_vector_type(8)));
typedef _Float16 half4v __attribute__((ext_vector_type(4)));
typedef float    floatx4 __attribute__((ext_vector_type(4)));
typedef float    floatx16 __attribute__((ext_vector_type(16)));

// async global->LDS, 16B per lane; LDS dest = wave-uniform base + lane*16
#define GLDS(g, l) __builtin_amdgcn_global_load_lds( \
    (const __attribute__((address_space(1))) void*)(g), \
    (__attribute__((address_space(3))) void*)(l), 16, 0, 0)

// ---------------------------------------------------------------------------
// split fp32 -> hi/lo f16 (x = hi + lo, residual ~2^-22 rel)
// ---------------------------------------------------------------------------
__global__ void __launch_bounds__(256) split_f16(
    const float* __restrict__ src, _Float16* __restrict__ hi,
    _Float16* __restrict__ lo, int n4)
{
    int i = blockIdx.x * 256 + threadIdx.x;
    if (i >= n4) return;
    float4 v = ((const float4*)src)[i];
    half4v h, l;
    h[0] = (_Float16)v.x; h[1] = (_Float16)v.y;
    h[2] = (_Float16)v.z; h[3] = (_Float16)v.w;
    l[0] = (_Float16)(v.x - (float)h[0]); l[1] = (_Float16)(v.y - (float)h[1]);
    l[2] = (_Float16)(v.z - (float)h[2]); l[3] = (_Float16)(v.w - (float)h[3]);
    ((half4v*)hi)[i] = h;
    ((half4v*)lo)[i] = l;
}

// ---------------------------------------------------------------------------
// transpose + split: dst[c][r] = src[z][r][c], dst ld = R. (weights pack)
// grid: (C/32, R/32, Z)
// ---------------------------------------------------------------------------
__global__ void __launch_bounds__(256) transpose_split(
    const float* __restrict__ src, _Float16* __restrict__ hi,
    _Float16* __restrict__ lo, int R, int C)
{
    __shared__ float T[32][33];
    const int tid = threadIdx.x;
    const long zo = (long)blockIdx.z * R * C;
    const int r0 = blockIdx.y * 32, c0 = blockIdx.x * 32;
#pragma unroll
    for (int p = 0; p < 4; ++p) {
        int i = tid + p * 256;
        int lr = i >> 5, lc = i & 31;
        T[lr][lc] = src[zo + (long)(r0 + lr) * C + (c0 + lc)];
    }
    __syncthreads();
#pragma unroll
    for (int p = 0; p < 4; ++p) {
        int i = tid + p * 256;
        int orr = i >> 5, oc = i & 31;
        float v = T[oc][orr];
        _Float16 h = (_Float16)v;
        long o = zo + (long)(c0 + orr) * R + (r0 + oc);
        hi[o] = h;
        lo[o] = (_Float16)(v - (float)h);
    }
}

// ---------------------------------------------------------------------------
// mask -> per-64g-tile 64-bit bitmap (bit g set iff mask byte nonzero)
// grid 2 x 256: thread t handles (b = t>>5, tile = t&31); ulong-vector loads
// ---------------------------------------------------------------------------
__global__ void __launch_bounds__(256) mask_bitmap(
    const unsigned char* __restrict__ mask, unsigned long long* __restrict__ bmp)
{
    const int t = blockIdx.x * 256 + threadIdx.x;
    const int b = t >> 5, tile = t & 31;
    const unsigned long long* m8 =
        (const unsigned long long*)(mask + (long)b * G_ + tile * 64);
    unsigned long long v = 0ULL;
#pragma unroll
    for (int i = 0; i < 8; ++i) {
        const unsigned long long w = m8[i];
#pragma unroll
        for (int j = 0; j < 8; ++j)
            v |= (((w >> (8 * j)) & 0xFFULL) ? 1ULL : 0ULL) << (8 * i + j);
    }
    bmp[t] = v;
}

// ---------------------------------------------------------------------------
// f16x3 MFMA GEMM (NT): C = alpha * (Ah+Al)(M x 512) @ (Bh+Bl)(N x 512)^T
// 128x128 tile, 4 waves (64x64 each, 4x4 of 16x16x32 MFMA), BK=32.
// 2-PHASE double-buffered staging: STAGE of K-step t+1 is issued right after
// the barrier for t, so HBM/L2 latency hides under t's ds_read+MFMA phase.
// One vmcnt(0)+barrier per K-step (at loop top).
// A,B k-major ld=512. C (fp32) nullable; split output (Chi/Clo) nullable.
// z: A rows += z*sAz, B rows += z*sBz, C += z*sCz.
// ---------------------------------------------------------------------------
__global__ void __launch_bounds__(256) gemm_f16x3(
    const _Float16* __restrict__ Ah, const _Float16* __restrict__ Al,
    const _Float16* __restrict__ Bh, const _Float16* __restrict__ Bl,
    float* __restrict__ C, _Float16* __restrict__ Chi, _Float16* __restrict__ Clo,
    long ldc, long sAz, long sBz, long sCz, float alpha)
{
    __shared__ _Float16 Ash[2][128 * 32], Asl[2][128 * 32];
    __shared__ _Float16 Bsh[2][128 * 32], Bsl[2][128 * 32];
    const int tid = threadIdx.x;
    const int w = tid >> 6, lane = tid & 63;
    const int quad = lane >> 4, tn = lane & 15;
    const int wm = (w >> 1) * 64, wn = (w & 1) * 64;
    const int z = blockIdx.z;
    const long m0 = (long)blockIdx.y * 128;
    const long n0 = (long)blockIdx.x * 128;
    const _Float16* Agh = Ah + (z * sAz + m0) * 512;
    const _Float16* Agl = Al + (z * sAz + m0) * 512;
    const _Float16* Bgh = Bh + (z * sBz + n0) * 512;
    const _Float16* Bgl = Bl + (z * sBz + n0) * 512;
    const long glane = (long)(lane >> 2) * 512 + (lane & 3) * 8;

#define STAGE_G(buf, kk0) do { \
    _Pragma("unroll") \
    for (int cc = 0; cc < 2; ++cc) { \
        const int c = 2 * w + cc; \
        const long go = (long)c * 16 * 512 + glane + (kk0); \
        GLDS(Agh + go, &Ash[buf][c * 512]); \
        GLDS(Agl + go, &Asl[buf][c * 512]); \
        GLDS(Bgh + go, &Bsh[buf][c * 512]); \
        GLDS(Bgl + go, &Bsl[buf][c * 512]); \
    } } while (0)

    STAGE_G(0, 0);                               // prologue

    floatx4 acc[4][4] = {};

    for (int k0 = 0; k0 < 512; k0 += 32) {
        const int cur = (k0 >> 5) & 1;
        asm volatile("s_waitcnt vmcnt(0)" ::: "memory");   // buf[cur] data landed
        __syncthreads();                                   // all waves see it
        if (k0 + 32 < 512) STAGE_G(cur ^ 1, k0 + 32);      // prefetch overlaps MFMA

        half8 ah[4], al[4], bh[4], bl[4];
#pragma unroll
        for (int t = 0; t < 4; ++t) {
            ah[t] = *(const half8*)&Ash[cur][(wm + t * 16 + tn) * 32 + quad * 8];
            al[t] = *(const half8*)&Asl[cur][(wm + t * 16 + tn) * 32 + quad * 8];
            bh[t] = *(const half8*)&Bsh[cur][(wn + t * 16 + tn) * 32 + quad * 8];
            bl[t] = *(const half8*)&Bsl[cur][(wn + t * 16 + tn) * 32 + quad * 8];
        }
#pragma unroll
        for (int i = 0; i < 4; ++i)
#pragma unroll
            for (int j = 0; j < 4; ++j) {
                acc[i][j] = __builtin_amdgcn_mfma_f32_16x16x32_f16(ah[i], bh[j], acc[i][j], 0, 0, 0);
                acc[i][j] = __builtin_amdgcn_mfma_f32_16x16x32_f16(ah[i], bl[j], acc[i][j], 0, 0, 0);
                acc[i][j] = __builtin_amdgcn_mfma_f32_16x16x32_f16(al[i], bh[j], acc[i][j], 0, 0, 0);
            }
        // no trailing barrier: next iteration's top barrier protects buf reuse
    }
#undef STAGE_G

#pragma unroll
    for (int i = 0; i < 4; ++i) {
        const long row0 = m0 + wm + i * 16 + quad * 4;
#pragma unroll
        for (int r = 0; r < 4; ++r) {
            const long row = row0 + r;
#pragma unroll
            for (int j = 0; j < 4; ++j) {
                float v = acc[i][j][r] * alpha;
                const long o = (long)z * sCz + row * ldc + n0 + wn + j * 16 + tn;
                if (C) C[o] = v;
                if (Chi) {
                    _Float16 hh = (_Float16)v;
                    Chi[o] = hh;
                    Clo[o] = (_Float16)(v - (float)hh);
                }
            }
        }
    }
}

// ---------------------------------------------------------------------------
// MFMA flash attention, f16x3, 32x32x16 MFMA, swapped-operand QK^T so P is
// lane-local (no P LDS round-trip). 256 thr = 4 waves; wave owns 32 s-rows;
// block = 128 s x 512 g (G split in 4 quarters). Unnormalized partial O +
// row-sums out (no-max softmax => partials add); combine_flash normalizes.
// ---------------------------------------------------------------------------
__global__ void __launch_bounds__(256) flash_mfma(
    const _Float16* __restrict__ qh, const _Float16* __restrict__ qlo,
    const _Float16* __restrict__ kh, const _Float16* __restrict__ kl,
    const _Float16* __restrict__ vh, const _Float16* __restrict__ vl,
    const unsigned long long* __restrict__ bmp,
    float* __restrict__ Opart, float* __restrict__ Lpart)
{
    __shared__ half8 KH[512], KL[512], VH[512], VL[512];   // 64 rows x 8 gran, 32KB
    const int tid = threadIdx.x;
    const int wid = tid >> 6, lane = tid & 63;
    const int lh = lane >> 5, ln = lane & 31;
    const int head = blockIdx.y, b = blockIdx.z;
    const int sblk = blockIdx.x & 1, gq = blockIdx.x >> 1;   // 2 s-halves x 4 g-quarters
    const long tok0 = (long)b * S_ + sblk * 128 + wid * 32;

    // Q fragments (B-operand: col = ln = s, k = ks*16 + lh*8 + e), loaded once
    const long qoff = (tok0 + ln) * 512 + head * 64 + lh * 8;
    half8 qfh[4], qfl[4];
#pragma unroll
    for (int ks = 0; ks < 4; ++ks) {
        qfh[ks] = *(const half8*)(qh + qoff + ks * 16);
        qfl[ks] = *(const half8*)(qlo + qoff + ks * 16);
    }

    // staging roles: wave wid stages row-chunks c = 2*wid, 2*wid+1 (8 rows x 8 gran)
    const int srow_lo = lane >> 3;          // row within chunk
    const int sgs = lane & 7;               // dest granule slot (linear in lane)
    const long kgK = (long)b * G_ * 512 + head * 64;
    const long kgV = (long)head * 64 * (B_ * G_) + (long)b * G_;

    floatx16 accO[2] = {};
    float lsum = 0.f;

    for (int t = 0; t < 8; ++t) {
        const int g0 = gq * 512 + t * 64;
        // ---- stage K/V tile: linear LDS dest, inverse-swizzled global source
#pragma unroll
        for (int cc = 0; cc < 2; ++cc) {
            const int c = 2 * wid + cc;
            const int r = c * 8 + srow_lo;
            const int gs = sgs ^ (r & 7);
            const long ko = kgK + (long)(g0 + r) * 512 + gs * 8;
            const long vo = kgV + (long)r * (B_ * G_) + g0 + gs * 8;
            GLDS(kh + ko, KH + c * 64);
            GLDS(kl + ko, KL + c * 64);
            GLDS(vh + vo, VH + c * 64);
            GLDS(vl + vo, VL + c * 64);
        }
        asm volatile("s_waitcnt vmcnt(0)" ::: "memory");
        __syncthreads();

        // ---- scores^T = K Q^T (A=K, B=Q): lane holds col s=ln, rows=g spread
        floatx16 accS[2] = {};
#pragma unroll
        for (int gt = 0; gt < 2; ++gt) {
            const int grow = gt * 32 + ln;
            const int gbase = grow * 8, gswz = grow & 7;
#pragma unroll
            for (int ks = 0; ks < 4; ++ks) {
                const int gi = gbase + ((ks * 2 + lh) ^ gswz);
                half8 kbh = KH[gi], kbl = KL[gi];
                accS[gt] = __builtin_amdgcn_mfma_f32_32x32x16_f16(kbh, qfh[ks], accS[gt], 0, 0, 0);
                accS[gt] = __builtin_amdgcn_mfma_f32_32x32x16_f16(kbh, qfl[ks], accS[gt], 0, 0, 0);
                accS[gt] = __builtin_amdgcn_mfma_f32_32x32x16_f16(kbl, qfh[ks], accS[gt], 0, 0, 0);
            }
        }

        // ---- mask via uniform bitmap (skipped entirely when no bits set) ----
        const unsigned long long bm = bmp[(b << 5) + (g0 >> 6)];
        if (bm != 0ULL) {
            const unsigned w0 = lh ? ((unsigned)bm >> 4) : (unsigned)bm;
            const unsigned w1 = lh ? ((unsigned)(bm >> 32) >> 4) : (unsigned)(bm >> 32);
#pragma unroll
            for (int gt = 0; gt < 2; ++gt) {
                const unsigned wsel = gt ? w1 : w0;
#pragma unroll
                for (int r = 0; r < 16; ++r) {
                    const int sh = (r & 3) + 8 * (r >> 2);
                    if ((wsel >> sh) & 1u) accS[gt][r] = -1.0e9f;
                }
            }
        }

        // ---- p = exp2(s); row-sum = in-lane add + one cross-half exchange ----
        float rs = 0.f;
#pragma unroll
        for (int gt = 0; gt < 2; ++gt)
#pragma unroll
            for (int r = 0; r < 16; ++r) {
                const float pv = __builtin_exp2f(accS[gt][r]);
                accS[gt][r] = pv;
                rs += pv;
            }
        rs += __shfl_xor(rs, 32);
        lsum += rs;

        // ---- O += P V : assemble A-frag of P in registers (shfl across halves)
#pragma unroll
        for (int gt = 0; gt < 2; ++gt)
#pragma unroll
            for (int w = 0; w < 2; ++w) {
                half8 ph, pl;
#pragma unroll
                for (int j = 0; j < 4; ++j) {
                    const float pA = accS[gt][8 * w + j];
                    const float pB = accS[gt][8 * w + 4 + j];
                    const float snd = lh ? pA : pB;
                    const float rcv = __shfl_xor(snd, 32);
                    const float e03 = lh ? rcv : pA;
                    const float e47 = lh ? pB : rcv;
                    float hi = __uint_as_float(__float_as_uint(e03) & 0xFFFFE000u);
                    ph[j] = (_Float16)hi;
                    pl[j] = (_Float16)(e03 - hi);
                    hi = __uint_as_float(__float_as_uint(e47) & 0xFFFFE000u);
                    ph[4 + j] = (_Float16)hi;
                    pl[4 + j] = (_Float16)(e47 - hi);
                }
                const int gvb = gt * 4 + w * 2 + lh;
#pragma unroll
                for (int nt = 0; nt < 2; ++nt) {
                    const int vrow = nt * 32 + ln;
                    const int gi = vrow * 8 + (gvb ^ (vrow & 7));
                    half8 vbh = VH[gi], vbl = VL[gi];
                    accO[nt] = __builtin_amdgcn_mfma_f32_32x32x16_f16(ph, vbh, accO[nt], 0, 0, 0);
                    accO[nt] = __builtin_amdgcn_mfma_f32_32x32x16_f16(ph, vbl, accO[nt], 0, 0, 0);
                    accO[nt] = __builtin_amdgcn_mfma_f32_32x32x16_f16(pl, vbh, accO[nt], 0, 0, 0);
                }
            }
        __syncthreads();
    }

    // ---- epilogue: unnormalized partial O + row-sums for this G-quarter ----
    float* Op = Opart + (long)gq * (4096L * 512);
#pragma unroll
    for (int nt = 0; nt < 2; ++nt)
#pragma unroll
        for (int r = 0; r < 16; ++r) {
            const int s = (r & 3) + 8 * (r >> 2) + 4 * lh;
            Op[(tok0 + s) * 512 + head * 64 + nt * 32 + ln] = accO[nt][r];
        }
    if (lane < 32)
        Lpart[(long)gq * 32768 + (tok0 + lane) * 8 + head] = lsum;
}

// ---------------------------------------------------------------------------
// combine the four G-quarter partials: heads = sum(O)/sum(l), split hi/lo f16
// ---------------------------------------------------------------------------
__global__ void __launch_bounds__(256) combine_flash(
    const float* __restrict__ Op, const float* __restrict__ Lp,
    _Float16* __restrict__ hd_hi, _Float16* __restrict__ hd_lo)
{
    const int idx = blockIdx.x * 256 + threadIdx.x;
    const int n = idx >> 7;
    const int c = (idx & 127) * 4;
    const int h = c >> 6;
    float l = 0.f;
#pragma unroll
    for (int q = 0; q < 4; ++q) l += Lp[q * 32768 + (long)n * 8 + h];
    const float inv = 1.0f / l;
    float4 a = *(const float4*)(Op + (long)n * 512 + c);
#pragma unroll
    for (int q = 1; q < 4; ++q) {
        float4 d = *(const float4*)(Op + (long)q * 2097152 + (long)n * 512 + c);
        a.x += d.x; a.y += d.y; a.z += d.z; a.w += d.w;
    }
    const float ox = a.x * inv, oy = a.y * inv, oz = a.z * inv, ow = a.w * inv;
    half4v hh, ll;
    hh[0] = (_Float16)ox; hh[1] = (_Float16)oy;
    hh[2] = (_Float16)oz; hh[3] = (_Float16)ow;
    ll[0] = (_Float16)(ox - (float)hh[0]); ll[1] = (_Float16)(oy - (float)hh[1]);
    ll[2] = (_Float16)(oz - (float)hh[2]); ll[3] = (_Float16)(ow - (float)hh[3]);
    *(half4v*)(hd_hi + (long)n * 512 + c) = hh;
    *(half4v*)(hd_lo + (long)n * 512 + c) = ll;
}

// ---------------------------------------------------------------------------
// Gate: logits = glimpse @ w_gate (glimpse as hi/lo f16), top-2, softmax
// 64 blocks x 64 tokens (256 thr: all stage, wave 0 computes) -> gates[n][8]
// ---------------------------------------------------------------------------
__global__ void __launch_bounds__(256) gate_topk(
    const _Float16* __restrict__ Xh, const _Float16* __restrict__ Xl,
    const float* __restrict__ wg, float* __restrict__ gates)
{
    __shared__ float W[512][8];
    __shared__ float Xs[64][37];
    const int tid = threadIdx.x;
    const int n0 = blockIdx.x * 64;
#pragma unroll
    for (int p = 0; p < 16; ++p) ((float*)W)[tid + p * 256] = wg[tid + p * 256];

    float acc[8] = {};
    for (int dc = 0; dc < 512; dc += 32) {
        __syncthreads();
#pragma unroll
        for (int p = 0; p < 2; ++p) {
            int f = tid + p * 256;
            int row = f >> 3, c4 = f & 7;
            long o = (long)(n0 + row) * 512 + dc + 4 * c4;
            half4v hv = *(const half4v*)(Xh + o);
            half4v lv = *(const half4v*)(Xl + o);
#pragma unroll
            for (int i = 0; i < 4; ++i) Xs[row][4 * c4 + i] = (float)hv[i] + (float)lv[i];
        }
        __syncthreads();
        if (tid < 64) {
            for (int d2 = 0; d2 < 32; ++d2) {
                float xv = Xs[tid][d2];
#pragma unroll
                for (int e = 0; e < 8; ++e) acc[e] += xv * W[dc + d2][e];
            }
        }
    }
    if (tid < 64) {
        float v1 = -3.0e38f; int i1 = 0;
#pragma unroll
        for (int e = 0; e < 8; ++e) if (acc[e] > v1) { v1 = acc[e]; i1 = e; }
        float v2 = -3.0e38f; int i2 = -1;
#pragma unroll
        for (int e = 0; e < 8; ++e) if (e != i1 && acc[e] > v2) { v2 = acc[e]; i2 = e; }
        float t = __expf(v2 - v1);
        float g1 = 1.0f / (1.0f + t);
        float g2 = t / (1.0f + t);
#pragma unroll
        for (int e = 0; e < 8; ++e)
            gates[(long)(n0 + tid) * 8 + e] = (e == i1) ? g1 : ((e == i2) ? g2 : 0.0f);
    }
}

// ---------------------------------------------------------------------------
// combine: gm = sum_e gates[n][e] * eo[e][n][:]  -> split hi/lo f16
// ---------------------------------------------------------------------------
__global__ void __launch_bounds__(256) combine_moe(
    const float* __restrict__ eo, const float* __restrict__ gates,
    _Float16* __restrict__ gh, _Float16* __restrict__ gl)
{
    const int idx = blockIdx.x * 256 + threadIdx.x;
    const int n = idx >> 7;
    const int c = (idx & 127) * 4;
    float g[8];
#pragma unroll
    for (int e = 0; e < 8; ++e) g[e] = gates[(long)n * 8 + e];
    float ax = 0.f, ay = 0.f, az = 0.f, aw = 0.f;
#pragma unroll
    for (int e = 0; e < 8; ++e) {
        if (g[e] != 0.0f) {
            float4 v = *(const float4*)(eo + (long)e * 2097152 + (long)n * 512 + c);
            ax += g[e] * v.x; ay += g[e] * v.y; az += g[e] * v.z; aw += g[e] * v.w;
        }
    }
    half4v h, l;
    h[0] = (_Float16)ax; h[1] = (_Float16)ay; h[2] = (_Float16)az; h[3] = (_Float16)aw;
    l[0] = (_Float16)(ax - (float)h[0]); l[1] = (_Float16)(ay - (float)h[1]);
    l[2] = (_Float16)(az - (float)h[2]); l[3] = (_Float16)(aw - (float)h[3]);
    *(half4v*)(gh + (long)n * 512 + c) = h;
    *(half4v*)(gl + (long)n * 512 + c) = l;
}

// ---------------------------------------------------------------------------
extern "C" void kernel_launch(void* const* d_in, const int* in_sizes, int n_in,
                              void* d_out, int out_size, void* d_ws, size_t ws_size,
                              hipStream_t stream) {
    const float* query     = (const float*)d_in[0];
    const float* key       = (const float*)d_in[1];
    // d_in[2] = value: UNUSED by the reference (V is projected from `key`)
    const float* logit_key = (const float*)d_in[3];
    const unsigned char* mask = (const unsigned char*)d_in[4];
    const float* Wq = (const float*)d_in[5];
    const float* Wk = (const float*)d_in[6];
    const float* Wv = (const float*)d_in[7];
    const float* Wo = (const float*)d_in[8];
    const float* wg = (const float*)d_in[9];
    const float* Ew = (const float*)d_in[10];
    float* out = (float*)d_out;

    // ---- workspace map (1 MB = 1048576 B); aliases annotated ----
    const size_t MBy = 1048576;
    char* W = (char*)d_ws;
    _Float16* q_hi  = (_Float16*)(W + 0 * MBy);    // projected Q (scaled), 4 MB each
    _Float16* q_lo  = (_Float16*)(W + 4 * MBy);
    _Float16* kp_hi = (_Float16*)(W + 8 * MBy);    // projected K, 32 MB each
    _Float16* kp_lo = (_Float16*)(W + 40 * MBy);
    _Float16* vt_hi = (_Float16*)(W + 72 * MBy);   // projected V^T [512][32768]
    _Float16* vt_lo = (_Float16*)(W + 104 * MBy);
    _Float16* kin_hi = (_Float16*)(W + 136 * MBy); // key split (dead after VT-proj)
    _Float16* kin_lo = (_Float16*)(W + 168 * MBy);
    float*    Opart = (float*)(W + 136 * MBy);     // flash partial O, 4x8MB (alias kin)
    float*    Lpart = (float*)(W + 168 * MBy);     // flash partial row-sums, 4x128KB
    float*    eo    = (float*)(W + 136 * MBy);     // expert_out 64MB (alias, after)
    _Float16* lk_hi = (_Float16*)(W + 136 * MBy);  // logit_key split (after combine)
    _Float16* lk_lo = (_Float16*)(W + 168 * MBy);
    _Float16* wq_hi = (_Float16*)(W + 204 * MBy);
    _Float16* wq_lo = (_Float16*)(W + 204 * MBy + 524288);
    _Float16* wk_hi = (_Float16*)(W + 205 * MBy);
    _Float16* wk_lo = (_Float16*)(W + 205 * MBy + 524288);
    _Float16* wv_hi = (_Float16*)(W + 206 * MBy);
    _Float16* wv_lo = (_Float16*)(W + 206 * MBy + 524288);
    _Float16* wo_hi = (_Float16*)(W + 207 * MBy);
    _Float16* wo_lo = (_Float16*)(W + 207 * MBy + 524288);
    _Float16* ew_hi = (_Float16*)(W + 208 * MBy);
    _Float16* ew_lo = (_Float16*)(W + 212 * MBy);
    _Float16* qi_hi = (_Float16*)(W + 216 * MBy);  // query split (dead after Q-proj)
    _Float16* qi_lo = (_Float16*)(W + 220 * MBy);
    _Float16* hd_hi = (_Float16*)(W + 216 * MBy);  // heads (alias qi, after)
    _Float16* hd_lo = (_Float16*)(W + 220 * MBy);
    _Float16* gl_hi = (_Float16*)(W + 224 * MBy);  // glimpse
    _Float16* gl_lo = (_Float16*)(W + 228 * MBy);
    _Float16* gm_hi = (_Float16*)(W + 232 * MBy);  // moe output
    _Float16* gm_lo = (_Float16*)(W + 236 * MBy);
    float*    gates = (float*)(W + 240 * MBy);     // 128 KB
    unsigned long long* bmp = (unsigned long long*)(W + 240 * MBy + 131072); // 4 KB

    dim3 blk(256);

    // ---- input splits / weight packs / mask bitmap ----
    split_f16<<<dim3(16384), blk, 0, stream>>>(key, kin_hi, kin_lo, 4194304);
    split_f16<<<dim3(2048), blk, 0, stream>>>(query, qi_hi, qi_lo, 524288);
    mask_bitmap<<<dim3(2), blk, 0, stream>>>(mask, bmp);
    transpose_split<<<dim3(2, 16, 8), blk, 0, stream>>>(Wq, wq_hi, wq_lo, 512, 64);
    transpose_split<<<dim3(2, 16, 8), blk, 0, stream>>>(Wk, wk_hi, wk_lo, 512, 64);
    transpose_split<<<dim3(2, 16, 8), blk, 0, stream>>>(Wv, wv_hi, wv_lo, 512, 64);
    transpose_split<<<dim3(16, 16, 1), blk, 0, stream>>>(Wo, wo_hi, wo_lo, 512, 512);
    transpose_split<<<dim3(16, 16, 8), blk, 0, stream>>>(Ew, ew_hi, ew_lo, 512, 512);

    // ---- projections (f16x3 MFMA, f16 hi/lo outputs only) ----
    // Q scaled by log2e/sqrt(DK) so flash uses exp2 with no per-score multiply
    gemm_f16x3<<<dim3(4, 32, 1), blk, 0, stream>>>(
        qi_hi, qi_lo, wq_hi, wq_lo, nullptr, q_hi, q_lo, 512, 0, 0, 0,
        0.1803368801111204f);
    gemm_f16x3<<<dim3(4, 256, 1), blk, 0, stream>>>(
        kin_hi, kin_lo, wk_hi, wk_lo, nullptr, kp_hi, kp_lo, 512, 0, 0, 0, 1.0f);
    // V^T = Wv^T @ key^T : A = wv pack (512x512 k-major), B = key split
    gemm_f16x3<<<dim3(256, 4, 1), blk, 0, stream>>>(
        wv_hi, wv_lo, kin_hi, kin_lo, nullptr, vt_hi, vt_lo, (long)B_ * G_,
        0, 0, 0, 1.0f);

    // ---- attention (32x32 MFMA f16x3, lane-local P, G split in 4) ----
    flash_mfma<<<dim3(8, H_, B_), blk, 0, stream>>>(
        q_hi, q_lo, kp_hi, kp_lo, vt_hi, vt_lo, bmp, Opart, Lpart);
    combine_flash<<<dim3(2048), blk, 0, stream>>>(Opart, Lpart, hd_hi, hd_lo);

    // ---- Wo merge -> glimpse (hi/lo) ----
    gemm_f16x3<<<dim3(4, 32, 1), blk, 0, stream>>>(
        hd_hi, hd_lo, wo_hi, wo_lo, nullptr, gl_hi, gl_lo, 512, 0, 0, 0, 1.0f);

    // ---- gating ----
    gate_topk<<<dim3(64), blk, 0, stream>>>(gl_hi, gl_lo, wg, gates);

    // ---- MoE experts (dense over e; gates re-zero non-top2) ----
    gemm_f16x3<<<dim3(4, 32, 8), blk, 0, stream>>>(
        gl_hi, gl_lo, ew_hi, ew_lo, eo, nullptr, nullptr, 512, 0, 512, 2097152, 1.0f);

    // ---- gate-weighted combine -> gm (hi/lo) ----
    combine_moe<<<dim3(2048), blk, 0, stream>>>(eo, gates, gm_hi, gm_lo);

    // ---- logit_key split (after eo consumed; aliases its region) ----
    split_f16<<<dim3(16384), blk, 0, stream>>>(logit_key, lk_hi, lk_lo, 4194304);

    // ---- final logits: out[b] = gm[b] @ lk[b]^T / sqrt(512) ----
    gemm_f16x3<<<dim3(16, 2, 16), blk, 0, stream>>>(
        gm_hi, gm_lo, lk_hi, lk_lo, out, nullptr, nullptr, 2048,
        256, 2048, 524288, 0.04419417382415922f);
}